// Round 7
// baseline (241.117 us; speedup 1.0000x reference)
//
#include <hip/hip_runtime.h>

// ---------------- constants ----------------
#define BATCH   2
#define NSEQ    2048
#define DMODEL  1024
#define HEADS   16
#define DHEAD   64
#define INNER   1024      // HEADS*DHEAD
#define NCOL    3072      // 3*INNER
#define BNROWS  4096      // BATCH*NSEQ
#define KDIM    1024      // contraction dim for both GEMMs
#define NQT     (NSEQ / 32)

typedef unsigned short ushort;
typedef unsigned int   uint;
typedef __attribute__((ext_vector_type(8)))  short  short8;
typedef __attribute__((ext_vector_type(4)))  float  f32x4;
typedef __attribute__((ext_vector_type(16))) float  f32x16;
typedef __attribute__((ext_vector_type(8)))  ushort ushort8;
typedef __attribute__((ext_vector_type(4)))  float  f4v;
typedef __attribute__((ext_vector_type(4)))  uint   uint4v;

// SCALE * log2(e) so softmax can use exp2 directly
#define QSCALE 0.1803368801111204f   // 64^-0.5 * 1.4426950408889634

__device__ __forceinline__ ushort f2bf(float f) {
  uint u = __builtin_bit_cast(uint, f);
  u += 0x7fffu + ((u >> 16) & 1u);   // RNE
  return (ushort)(u >> 16);
}
__device__ __forceinline__ uint pkbf(float a, float b) {
  return (uint)f2bf(a) | ((uint)f2bf(b) << 16);
}

__device__ __forceinline__ f32x4 mfma16(short8 a, short8 b, f32x4 c) {
  return __builtin_amdgcn_mfma_f32_16x16x32_bf16(a, b, c, 0, 0, 0);
}
__device__ __forceinline__ f32x16 mfma32(short8 a, short8 b, f32x16 c) {
  return __builtin_amdgcn_mfma_f32_32x32x16_bf16(a, b, c, 0, 0, 0);
}

#define GLDS(gp, lp) __builtin_amdgcn_global_load_lds( \
    (const __attribute__((address_space(1))) void*)(gp), \
    (__attribute__((address_space(3))) void*)(lp), 16, 0, 0)

// ---------------- lengths from mask (int32 0/1) ----------------
__global__ __launch_bounds__(256) void lens_kernel(const int* __restrict__ mask,
                                                   int* __restrict__ lens) {
  __shared__ int sm[256];
  int b = blockIdx.x, t = threadIdx.x;
  int s = 0;
  for (int i = t; i < NSEQ; i += 256) s += (mask[b * NSEQ + i] != 0);
  sm[t] = s;
  __syncthreads();
  for (int off = 128; off > 0; off >>= 1) {
    if (t < off) sm[t] += sm[t + off];
    __syncthreads();
  }
  if (t == 0) lens[b] = sm[0];
}

// ---------------- fp32 -> bf16 cast (vectorized) ----------------
__global__ __launch_bounds__(256) void cast_bf16_kernel(const float* __restrict__ x,
                                                        ushort* __restrict__ y, int n8) {
  int i = blockIdx.x * 256 + threadIdx.x;
  if (i >= n8) return;
  const f4v* xv = (const f4v*)x;
  f4v a = xv[(size_t)i * 2], b = xv[(size_t)i * 2 + 1];
  ushort8 o;
  o[0] = f2bf(a[0]); o[1] = f2bf(a[1]); o[2] = f2bf(a[2]); o[3] = f2bf(a[3]);
  o[4] = f2bf(b[0]); o[5] = f2bf(b[1]); o[6] = f2bf(b[2]); o[7] = f2bf(b[3]);
  ((ushort8*)y)[i] = o;
}

// ---------------- fp32 (K,C) -> bf16 transposed (C,K) ----------------
__global__ __launch_bounds__(256) void transpose_bf16_kernel(const float* __restrict__ W,
                                                             ushort* __restrict__ Wt,
                                                             int K, int C) {
  __shared__ float tile[32][33];
  int c0 = blockIdx.x * 32, k0 = blockIdx.y * 32;
  int tx = threadIdx.x, ty = threadIdx.y;   // (32,8)
#pragma unroll
  for (int i = 0; i < 4; ++i)
    tile[ty + i * 8][tx] = W[(size_t)(k0 + ty + i * 8) * C + c0 + tx];
  __syncthreads();
#pragma unroll
  for (int i = 0; i < 4; ++i)
    Wt[(size_t)(c0 + ty + i * 8) * K + k0 + tx] = f2bf(tile[tx][ty + i * 8]);
}

// ---------------- bf16 (bh, n, d) -> (bh, d, n) transpose for V ----------------
__global__ __launch_bounds__(256) void vtrans_kernel(const ushort* __restrict__ v,
                                                     ushort* __restrict__ vt) {
  __shared__ ushort t[32][34];
  int d0 = blockIdx.x * 32, n0 = blockIdx.y * 32, bh = blockIdx.z;
  const ushort* vb  = v  + (size_t)bh * NSEQ * DHEAD;
  ushort*       vtb = vt + (size_t)bh * NSEQ * DHEAD;
  int tx = threadIdx.x, ty = threadIdx.y;   // (32,8)
#pragma unroll
  for (int i = 0; i < 4; ++i)
    t[ty + i * 8][tx] = vb[(size_t)(n0 + ty + i * 8) * DHEAD + d0 + tx];
  __syncthreads();
#pragma unroll
  for (int i = 0; i < 4; ++i)
    vtb[(size_t)(d0 + ty + i * 8) * NSEQ + n0 + tx] = t[tx][ty + i * 8];
}

// ---------------- m97-style bf16 GEMM, C = A(M,K) @ Bt(N,K)^T ----------------
template <int EPI>
__global__ __launch_bounds__(256) void gemm_bt_kernel(
    const ushort* __restrict__ A, const ushort* __restrict__ Bt,
    ushort* __restrict__ q_out, ushort* __restrict__ k_out, ushort* __restrict__ v_out,
    const float* __restrict__ bias, float* __restrict__ outp) {
  __shared__ __align__(16) ushort lA[128 * 64];
  __shared__ __align__(16) ushort lB[128 * 64];
  const int tid = threadIdx.x;
  const int wv = tid >> 6, lane = tid & 63;
  const int wr = wv >> 1, wc = wv & 1;
  const int m0 = blockIdx.x * 128, n0 = blockIdx.y * 128;
  const int l15 = lane & 15, l4 = lane >> 4;

  f32x4 zero = {0.f, 0.f, 0.f, 0.f};
  f32x4 acc[4][4];
#pragma unroll
  for (int i = 0; i < 4; ++i)
#pragma unroll
    for (int j = 0; j < 4; ++j) acc[i][j] = zero;

  const char* Ab  = (const char*)A;
  const char* Bb  = (const char*)Bt;
  char* lAb = (char*)lA;
  char* lBb = (char*)lB;

  for (int kt = 0; kt < KDIM; kt += 64) {
#pragma unroll
    for (int t = 0; t < 4; ++t) {
      int o = wv * 4096 + t * 1024 + lane * 16;
      int row = o >> 7, cb = o & 127;
      GLDS(Ab + ((size_t)(m0 + row) * KDIM + kt) * 2 + cb, lAb + o);
      GLDS(Bb + ((size_t)(n0 + row) * KDIM + kt) * 2 + cb, lBb + o);
    }
    __syncthreads();

    short8 af[4][2], bfr[4][2];
#pragma unroll
    for (int i = 0; i < 4; ++i) {
#pragma unroll
      for (int kc = 0; kc < 2; ++kc) {
        af[i][kc]  = *(const short8*)(lAb + (wr * 64 + i * 16 + l15) * 128 + kc * 64 + l4 * 16);
        bfr[i][kc] = *(const short8*)(lBb + (wc * 64 + i * 16 + l15) * 128 + kc * 64 + l4 * 16);
      }
    }
#pragma unroll
    for (int i = 0; i < 4; ++i)
#pragma unroll
      for (int j = 0; j < 4; ++j)
#pragma unroll
        for (int kc = 0; kc < 2; ++kc)
          acc[i][j] = mfma16(af[i][kc], bfr[j][kc], acc[i][j]);
    __syncthreads();
  }

#pragma unroll
  for (int i = 0; i < 4; ++i) {
#pragma unroll
    for (int j = 0; j < 4; ++j) {
#pragma unroll
      for (int r = 0; r < 4; ++r) {
        int grow = m0 + wr * 64 + i * 16 + l4 * 4 + r;
        int gcol = n0 + wc * 64 + j * 16 + l15;
        float v = acc[i][j][r];
        if (EPI == 0) {
          int b = grow >> 11, n = grow & (NSEQ - 1);
          int which = gcol >> 10, inner = gcol & 1023;
          int h = inner >> 6, dd = inner & 63;
          size_t off = ((size_t)(b * HEADS + h) * NSEQ + n) * DHEAD + dd;
          if (which == 0)
            q_out[off] = f2bf(v * QSCALE);
          else if (which == 1)
            k_out[off] = f2bf(v);
          else
            v_out[off] = f2bf(v);
        } else {
          outp[(size_t)grow * INNER + gcol] = v + bias[gcol];
        }
      }
    }
  }
}

// ---------------- flash attention: swapped-QK^T, in-register softmax ----------------
// 1 wave per 32-row Q tile, KBLK=64 (two 32-key sub-tiles per iter -> one joint
// softmax reduce/rescale per 64 keys, 16-MFMA clusters). Heaviest q-tiles
// launch FIRST (LPT) to kill the causal drain tail. bh in low bid bits keeps
// each XCD on 4 bh's K/V (2 MB < 4 MB L2).
__global__ __launch_bounds__(64) void attn_kernel(
    const ushort* __restrict__ q, const ushort* __restrict__ k,
    const ushort* __restrict__ vt, const int* __restrict__ lens,
    ushort* __restrict__ ctx) {
  const int lane = threadIdx.x;
  const int l31 = lane & 31, hi = lane >> 5;
  const int bid = blockIdx.x;
  const int bh = bid & 31;
  const int qt = (NQT - 1) - (bid >> 5);         // heavy tiles first
  const int b = bh >> 4, h = bh & 15;
  const int len = lens[b];
  const ushort* qb  = q  + (size_t)bh * NSEQ * DHEAD;
  const ushort* kbp = k  + (size_t)bh * NSEQ * DHEAD;
  const ushort* vtb = vt + (size_t)bh * DHEAD * NSEQ;

  const int qglob = qt * 32 + l31;
  const int qcap  = min(qglob, len - 1);         // valid keys: j <= qcap

  // Q fragments (B-operand of S^T mfma): q-row = l31, d-chunk = dk*16 + hi*8
  short8 qf[4];
#pragma unroll
  for (int dk = 0; dk < 4; ++dk)
    qf[dk] = *(const short8*)&qb[(size_t)(qt * 32 + l31) * DHEAD + dk * 16 + hi * 8];

  f32x16 Ot[2];
#pragma unroll
  for (int d0b = 0; d0b < 2; ++d0b)
#pragma unroll
    for (int r = 0; r < 16; ++r) Ot[d0b][r] = 0.f;
  float mrow = -3.0e38f, lsum = 0.f;

  const int kbend = min(qt, (len - 1) >> 5);     // last valid 32-key tile

  // K regs for the current pair of 32-key tiles
  short8 kk[2][4];
  {
    int t1 = min(1, kbend);
#pragma unroll
    for (int dk = 0; dk < 4; ++dk) {
      kk[0][dk] = *(const short8*)&kbp[(size_t)l31 * DHEAD + dk * 16 + hi * 8];
      kk[1][dk] = *(const short8*)&kbp[(size_t)(t1 * 32 + l31) * DHEAD + dk * 16 + hi * 8];
    }
  }

  int kb = 0;
  while (kb + 1 <= kbend) {
    // ---- S^T for both sub-tiles ----
    f32x16 S0, S1;
#pragma unroll
    for (int r = 0; r < 16; ++r) { S0[r] = 0.f; S1[r] = 0.f; }
    __builtin_amdgcn_s_setprio(1);
#pragma unroll
    for (int dk = 0; dk < 4; ++dk) S0 = mfma32(kk[0][dk], qf[dk], S0);
#pragma unroll
    for (int dk = 0; dk < 4; ++dk) S1 = mfma32(kk[1][dk], qf[dk], S1);
    __builtin_amdgcn_s_setprio(0);

    // ---- K prefetch for next pair (kk dead after the MFMAs above) ----
    {
      int p0 = min(kb + 2, kbend), p1 = min(kb + 3, kbend);
#pragma unroll
      for (int dk = 0; dk < 4; ++dk) {
        kk[0][dk] = *(const short8*)&kbp[(size_t)(p0 * 32 + l31) * DHEAD + dk * 16 + hi * 8];
        kk[1][dk] = *(const short8*)&kbp[(size_t)(p1 * 32 + l31) * DHEAD + dk * 16 + hi * 8];
      }
    }

    // ---- V fragments for both sub-tiles ----
    short8 vf[2][2][2];   // [tile][d0b][ks]
#pragma unroll
    for (int d0b = 0; d0b < 2; ++d0b)
#pragma unroll
      for (int ks = 0; ks < 2; ++ks) {
        size_t base = (size_t)(d0b * 32 + l31) * NSEQ + kb * 32 + ks * 16 + hi * 8;
        vf[0][d0b][ks] = *(const short8*)&vtb[base];
        vf[1][d0b][ks] = *(const short8*)&vtb[base + 32];
      }

    // ---- mask (wave-uniform fast path skips it) ----
    bool fastp = (kb + 2 <= qt) && (kb * 32 + 63 < len);
    if (!fastp) {
      int base = kb * 32 + 4 * hi;
#pragma unroll
      for (int r = 0; r < 16; ++r) {
        int c = (r & 3) + 8 * (r >> 2);
        if (base + c > qcap)      S0[r] = -3.0e38f;
        if (base + 32 + c > qcap) S1[r] = -3.0e38f;
      }
    }

    // ---- joint row max over 32 values: tree + one cross-half shfl ----
    float t[8];
#pragma unroll
    for (int i = 0; i < 8; ++i)
      t[i] = fmaxf(fmaxf(S0[2 * i], S0[2 * i + 1]), fmaxf(S1[2 * i], S1[2 * i + 1]));
    t[0] = fmaxf(t[0], t[1]); t[2] = fmaxf(t[2], t[3]);
    t[4] = fmaxf(t[4], t[5]); t[6] = fmaxf(t[6], t[7]);
    float pm = fmaxf(fmaxf(t[0], t[2]), fmaxf(t[4], t[6]));
    pm = fmaxf(pm, __shfl_xor(pm, 32));

    // ---- defer-max (T13, THR=8 in exp2 domain) ----
    if (!__all(pm <= mrow + 8.0f)) {
      float mnew = fmaxf(mrow, pm);
      float scale = exp2f(mrow - mnew);
      lsum *= scale;
#pragma unroll
      for (int d0b = 0; d0b < 2; ++d0b)
#pragma unroll
        for (int r = 0; r < 16; ++r) Ot[d0b][r] *= scale;
      mrow = mnew;
    }

    // ---- p = exp2(S - m); joint row sum ----
    float p0[16], p1[16];
#pragma unroll
    for (int r = 0; r < 16; ++r) { p0[r] = exp2f(S0[r] - mrow); p1[r] = exp2f(S1[r] - mrow); }
    float u[8];
#pragma unroll
    for (int i = 0; i < 8; ++i)
      u[i] = (p0[2 * i] + p0[2 * i + 1]) + (p1[2 * i] + p1[2 * i + 1]);
    float rs = ((u[0] + u[1]) + (u[2] + u[3])) + ((u[4] + u[5]) + (u[6] + u[7]));
    rs += __shfl_xor(rs, 32);
    lsum += rs;

    // ---- pack P to bf16; exchange halves to build P^T B-fragments ----
    uint Pw0[8], Pw1[8], Xw0[8], Xw1[8];
#pragma unroll
    for (int i = 0; i < 8; ++i) {
      Pw0[i] = pkbf(p0[2 * i], p0[2 * i + 1]);
      Pw1[i] = pkbf(p1[2 * i], p1[2 * i + 1]);
    }
#pragma unroll
    for (int i = 0; i < 8; ++i) {
      Xw0[i] = __shfl_xor(Pw0[i], 32);
      Xw1[i] = __shfl_xor(Pw1[i], 32);
    }
    uint4v a00 = { hi ? Xw0[2] : Pw0[0], hi ? Xw0[3] : Pw0[1],
                   hi ? Pw0[2] : Xw0[0], hi ? Pw0[3] : Xw0[1] };
    uint4v a01 = { hi ? Xw0[6] : Pw0[4], hi ? Xw0[7] : Pw0[5],
                   hi ? Pw0[6] : Xw0[4], hi ? Pw0[7] : Xw0[5] };
    uint4v a10 = { hi ? Xw1[2] : Pw1[0], hi ? Xw1[3] : Pw1[1],
                   hi ? Pw1[2] : Xw1[0], hi ? Pw1[3] : Xw1[1] };
    uint4v a11 = { hi ? Xw1[6] : Pw1[4], hi ? Xw1[7] : Pw1[5],
                   hi ? Pw1[6] : Xw1[4], hi ? Pw1[7] : Xw1[5] };
    short8 pb00 = __builtin_bit_cast(short8, a00);
    short8 pb01 = __builtin_bit_cast(short8, a01);
    short8 pb10 = __builtin_bit_cast(short8, a10);
    short8 pb11 = __builtin_bit_cast(short8, a11);

    // ---- O^T += V^T . P^T (both sub-tiles) ----
    __builtin_amdgcn_s_setprio(1);
#pragma unroll
    for (int d0b = 0; d0b < 2; ++d0b) {
      Ot[d0b] = mfma32(vf[0][d0b][0], pb00, Ot[d0b]);
      Ot[d0b] = mfma32(vf[0][d0b][1], pb01, Ot[d0b]);
      Ot[d0b] = mfma32(vf[1][d0b][0], pb10, Ot[d0b]);
      Ot[d0b] = mfma32(vf[1][d0b][1], pb11, Ot[d0b]);
    }
    __builtin_amdgcn_s_setprio(0);

    kb += 2;
  }

  // ---- tail: single 32-key tile (kk[0] holds tile kbend) ----
  if (kb <= kbend) {
    f32x16 S;
#pragma unroll
    for (int r = 0; r < 16; ++r) S[r] = 0.f;
    __builtin_amdgcn_s_setprio(1);
#pragma unroll
    for (int dk = 0; dk < 4; ++dk) S = mfma32(kk[0][dk], qf[dk], S);
    __builtin_amdgcn_s_setprio(0);

    short8 vf[2][2];
#pragma unroll
    for (int d0b = 0; d0b < 2; ++d0b)
#pragma unroll
      for (int ks = 0; ks < 2; ++ks)
        vf[d0b][ks] = *(const short8*)&vtb[(size_t)(d0b * 32 + l31) * NSEQ +
                                           kb * 32 + ks * 16 + hi * 8];

    bool fast = (kb < qt) && (kb * 32 + 31 < len);
    if (!fast) {
      int base = kb * 32 + 4 * hi;
#pragma unroll
      for (int r = 0; r < 16; ++r) {
        int c = (r & 3) + 8 * (r >> 2);
        if (base + c > qcap) S[r] = -3.0e38f;
      }
    }

    float t0 = fmaxf(S[0], S[1]),  t1 = fmaxf(S[2], S[3]);
    float t2 = fmaxf(S[4], S[5]),  t3 = fmaxf(S[6], S[7]);
    float t4 = fmaxf(S[8], S[9]),  t5 = fmaxf(S[10], S[11]);
    float t6 = fmaxf(S[12], S[13]), t7 = fmaxf(S[14], S[15]);
    t0 = fmaxf(t0, t1); t2 = fmaxf(t2, t3); t4 = fmaxf(t4, t5); t6 = fmaxf(t6, t7);
    float pm = fmaxf(fmaxf(t0, t2), fmaxf(t4, t6));
    pm = fmaxf(pm, __shfl_xor(pm, 32));

    if (!__all(pm <= mrow + 8.0f)) {
      float mnew = fmaxf(mrow, pm);
      float scale = exp2f(mrow - mnew);
      lsum *= scale;
#pragma unroll
      for (int d0b = 0; d0b < 2; ++d0b)
#pragma unroll
        for (int r = 0; r < 16; ++r) Ot[d0b][r] *= scale;
      mrow = mnew;
    }

    float p[16];
#pragma unroll
    for (int r = 0; r < 16; ++r) p[r] = exp2f(S[r] - mrow);
    float s0 = (p[0] + p[1]) + (p[2] + p[3]);
    float s1 = (p[4] + p[5]) + (p[6] + p[7]);
    float s2 = (p[8] + p[9]) + (p[10] + p[11]);
    float s3 = (p[12] + p[13]) + (p[14] + p[15]);
    float rs = (s0 + s1) + (s2 + s3);
    rs += __shfl_xor(rs, 32);
    lsum += rs;

    uint Pw[8], Xw[8];
#pragma unroll
    for (int i = 0; i < 8; ++i) Pw[i] = pkbf(p[2 * i], p[2 * i + 1]);
#pragma unroll
    for (int i = 0; i < 8; ++i) Xw[i] = __shfl_xor(Pw[i], 32);
    uint4v bw0 = { hi ? Xw[2] : Pw[0], hi ? Xw[3] : Pw[1],
                   hi ? Pw[2] : Xw[0], hi ? Pw[3] : Xw[1] };
    uint4v bw1 = { hi ? Xw[6] : Pw[4], hi ? Xw[7] : Pw[5],
                   hi ? Pw[6] : Xw[4], hi ? Pw[7] : Xw[5] };
    short8 pb0 = __builtin_bit_cast(short8, bw0);
    short8 pb1 = __builtin_bit_cast(short8, bw1);

    __builtin_amdgcn_s_setprio(1);
#pragma unroll
    for (int d0b = 0; d0b < 2; ++d0b) {
      Ot[d0b] = mfma32(vf[d0b][0], pb0, Ot[d0b]);
      Ot[d0b] = mfma32(vf[d0b][1], pb1, Ot[d0b]);
    }
    __builtin_amdgcn_s_setprio(0);
  }

  // ---- epilogue: O^T col = lane's q-row; rows are d (pairs contiguous) ----
  float inv = 1.0f / lsum;
  size_t rowbase = ((size_t)(b * NSEQ) + qglob) * INNER + h * DHEAD;
#pragma unroll
  for (int d0b = 0; d0b < 2; ++d0b) {
#pragma unroll
    for (int i = 0; i < 8; ++i) {
      int d = 2 * (i & 1) + 8 * (i >> 1) + 4 * hi;   // crow(2i,hi); pair (d, d+1)
      uint w = pkbf(Ot[d0b][2 * i] * inv, Ot[d0b][2 * i + 1] * inv);
      *(uint*)&ctx[rowbase + d0b * 32 + d] = w;
    }
  }
}

// ---------------- launcher ----------------
extern "C" void kernel_launch(void* const* d_in, const int* in_sizes, int n_in,
                              void* d_out, int out_size, void* d_ws, size_t ws_size,
                              hipStream_t stream) {
  const float* x    = (const float*)d_in[0];
  const int*   mask = (const int*)d_in[1];
  const float* Wqkv = (const float*)d_in[2];
  const float* Wout = (const float*)d_in[3];
  const float* bias = (const float*)d_in[4];
  float* out = (float*)d_out;

  const size_t QKV_ELEMS = (size_t)BATCH * HEADS * NSEQ * DHEAD;

  ushort* ws = (ushort*)d_ws;
  ushort* x_bf  = ws;
  ushort* wq_t  = x_bf  + (size_t)BNROWS * DMODEL;
  ushort* wo_t  = wq_t  + (size_t)NCOL * KDIM;
  ushort* q_bf  = wo_t  + (size_t)INNER * KDIM;
  ushort* k_bf  = q_bf  + QKV_ELEMS;
  ushort* v_bf  = k_bf  + QKV_ELEMS;
  ushort* ctx   = v_bf  + QKV_ELEMS;
  int* lens = (int*)(ctx + (size_t)BNROWS * INNER);
  ushort* vt_bf = x_bf;   // alias: x_bf dead after QKV GEMM

  lens_kernel<<<dim3(BATCH), dim3(256), 0, stream>>>(mask, lens);
  cast_bf16_kernel<<<dim3((BNROWS * DMODEL / 8 + 255) / 256), dim3(256), 0, stream>>>(
      x, x_bf, BNROWS * DMODEL / 8);
  transpose_bf16_kernel<<<dim3(NCOL / 32, KDIM / 32), dim3(32, 8), 0, stream>>>(
      Wqkv, wq_t, KDIM, NCOL);
  transpose_bf16_kernel<<<dim3(INNER / 32, KDIM / 32), dim3(32, 8), 0, stream>>>(
      Wout, wo_t, KDIM, INNER);

  gemm_bt_kernel<0><<<dim3(BNROWS / 128, NCOL / 128), dim3(256), 0, stream>>>(
      x_bf, wq_t, q_bf, k_bf, v_bf, nullptr, nullptr);

  vtrans_kernel<<<dim3(DHEAD / 32, NSEQ / 32, BATCH * HEADS), dim3(32, 8), 0, stream>>>(
      v_bf, vt_bf);

  attn_kernel<<<dim3(NQT * 32), dim3(64), 0, stream>>>(
      q_bf, k_bf, vt_bf, lens, ctx);

  gemm_bt_kernel<1><<<dim3(BNROWS / 128, INNER / 128), dim3(256), 0, stream>>>(
      ctx, wo_t, nullptr, nullptr, nullptr, bias, out);
}

// Round 9
// 237.528 us; speedup vs baseline: 1.0151x; 1.0151x over previous
//
#include <hip/hip_runtime.h>

// ---------------- constants ----------------
#define BATCH   2
#define NSEQ    2048
#define DMODEL  1024
#define HEADS   16
#define DHEAD   64
#define INNER   1024      // HEADS*DHEAD
#define NCOL    3072      // 3*INNER
#define BNROWS  4096      // BATCH*NSEQ
#define KDIM    1024      // contraction dim for both GEMMs

typedef unsigned short ushort;
typedef unsigned int   uint;
typedef __attribute__((ext_vector_type(8)))  short  short8;
typedef __attribute__((ext_vector_type(4)))  float  f32x4;
typedef __attribute__((ext_vector_type(16))) float  f32x16;
typedef __attribute__((ext_vector_type(8)))  ushort ushort8;
typedef __attribute__((ext_vector_type(4)))  float  f4v;
typedef __attribute__((ext_vector_type(4)))  uint   uint4v;

// SCALE * log2(e) so softmax can use exp2 directly
#define QSCALE 0.1803368801111204f   // 64^-0.5 * 1.4426950408889634

__device__ __forceinline__ ushort f2bf(float f) {
  uint u = __builtin_bit_cast(uint, f);
  u += 0x7fffu + ((u >> 16) & 1u);   // RNE
  return (ushort)(u >> 16);
}
// single-op packed f32->bf16 (T12; no builtin on gfx950, RNE)
__device__ __forceinline__ uint cvtpk(float a, float b) {
  uint r;
  asm("v_cvt_pk_bf16_f32 %0, %1, %2" : "=v"(r) : "v"(a), "v"(b));
  return r;
}

__device__ __forceinline__ f32x4 mfma16(short8 a, short8 b, f32x4 c) {
  return __builtin_amdgcn_mfma_f32_16x16x32_bf16(a, b, c, 0, 0, 0);
}
__device__ __forceinline__ f32x16 mfma32(short8 a, short8 b, f32x16 c) {
  return __builtin_amdgcn_mfma_f32_32x32x16_bf16(a, b, c, 0, 0, 0);
}

#define GLDS(gp, lp) __builtin_amdgcn_global_load_lds( \
    (const __attribute__((address_space(1))) void*)(gp), \
    (__attribute__((address_space(3))) void*)(lp), 16, 0, 0)

// ---------------- lengths from mask (int32 0/1) ----------------
__global__ __launch_bounds__(256) void lens_kernel(const int* __restrict__ mask,
                                                   int* __restrict__ lens) {
  __shared__ int sm[256];
  int b = blockIdx.x, t = threadIdx.x;
  int s = 0;
  for (int i = t; i < NSEQ; i += 256) s += (mask[b * NSEQ + i] != 0);
  sm[t] = s;
  __syncthreads();
  for (int off = 128; off > 0; off >>= 1) {
    if (t < off) sm[t] += sm[t + off];
    __syncthreads();
  }
  if (t == 0) lens[b] = sm[0];
}

// ---------------- fp32 -> bf16 cast (vectorized) ----------------
__global__ __launch_bounds__(256) void cast_bf16_kernel(const float* __restrict__ x,
                                                        ushort* __restrict__ y, int n8) {
  int i = blockIdx.x * 256 + threadIdx.x;
  if (i >= n8) return;
  const f4v* xv = (const f4v*)x;
  f4v a = xv[(size_t)i * 2], b = xv[(size_t)i * 2 + 1];
  ushort8 o;
  o[0] = f2bf(a[0]); o[1] = f2bf(a[1]); o[2] = f2bf(a[2]); o[3] = f2bf(a[3]);
  o[4] = f2bf(b[0]); o[5] = f2bf(b[1]); o[6] = f2bf(b[2]); o[7] = f2bf(b[3]);
  ((ushort8*)y)[i] = o;
}

// ---------------- fp32 (K,C) -> bf16 transposed (C,K) ----------------
__global__ __launch_bounds__(256) void transpose_bf16_kernel(const float* __restrict__ W,
                                                             ushort* __restrict__ Wt,
                                                             int K, int C) {
  __shared__ float tile[32][33];
  int c0 = blockIdx.x * 32, k0 = blockIdx.y * 32;
  int tx = threadIdx.x, ty = threadIdx.y;   // (32,8)
#pragma unroll
  for (int i = 0; i < 4; ++i)
    tile[ty + i * 8][tx] = W[(size_t)(k0 + ty + i * 8) * C + c0 + tx];
  __syncthreads();
#pragma unroll
  for (int i = 0; i < 4; ++i)
    Wt[(size_t)(c0 + ty + i * 8) * K + k0 + tx] = f2bf(tile[tx][ty + i * 8]);
}

// ---------------- bf16 (bh, n, d) -> (bh, d, n) transpose for V ----------------
__global__ __launch_bounds__(256) void vtrans_kernel(const ushort* __restrict__ v,
                                                     ushort* __restrict__ vt) {
  __shared__ ushort t[32][34];
  int d0 = blockIdx.x * 32, n0 = blockIdx.y * 32, bh = blockIdx.z;
  const ushort* vb  = v  + (size_t)bh * NSEQ * DHEAD;
  ushort*       vtb = vt + (size_t)bh * NSEQ * DHEAD;
  int tx = threadIdx.x, ty = threadIdx.y;   // (32,8)
#pragma unroll
  for (int i = 0; i < 4; ++i)
    t[ty + i * 8][tx] = vb[(size_t)(n0 + ty + i * 8) * DHEAD + d0 + tx];
  __syncthreads();
#pragma unroll
  for (int i = 0; i < 4; ++i)
    vtb[(size_t)(d0 + ty + i * 8) * NSEQ + n0 + tx] = t[tx][ty + i * 8];
}

// ---------------- m97-style bf16 GEMM, C = A(M,K) @ Bt(N,K)^T ----------------
template <int EPI>
__global__ __launch_bounds__(256) void gemm_bt_kernel(
    const ushort* __restrict__ A, const ushort* __restrict__ Bt,
    ushort* __restrict__ q_out, ushort* __restrict__ k_out, ushort* __restrict__ v_out,
    const float* __restrict__ bias, float* __restrict__ outp) {
  __shared__ __align__(16) ushort lA[128 * 64];
  __shared__ __align__(16) ushort lB[128 * 64];
  const int tid = threadIdx.x;
  const int wv = tid >> 6, lane = tid & 63;
  const int wr = wv >> 1, wc = wv & 1;
  const int m0 = blockIdx.x * 128, n0 = blockIdx.y * 128;
  const int l15 = lane & 15, l4 = lane >> 4;

  f32x4 zero = {0.f, 0.f, 0.f, 0.f};
  f32x4 acc[4][4];
#pragma unroll
  for (int i = 0; i < 4; ++i)
#pragma unroll
    for (int j = 0; j < 4; ++j) acc[i][j] = zero;

  const char* Ab  = (const char*)A;
  const char* Bb  = (const char*)Bt;
  char* lAb = (char*)lA;
  char* lBb = (char*)lB;

  for (int kt = 0; kt < KDIM; kt += 64) {
#pragma unroll
    for (int t = 0; t < 4; ++t) {
      int o = wv * 4096 + t * 1024 + lane * 16;
      int row = o >> 7, cb = o & 127;
      GLDS(Ab + ((size_t)(m0 + row) * KDIM + kt) * 2 + cb, lAb + o);
      GLDS(Bb + ((size_t)(n0 + row) * KDIM + kt) * 2 + cb, lBb + o);
    }
    __syncthreads();

    short8 af[4][2], bfr[4][2];
#pragma unroll
    for (int i = 0; i < 4; ++i) {
#pragma unroll
      for (int kc = 0; kc < 2; ++kc) {
        af[i][kc]  = *(const short8*)(lAb + (wr * 64 + i * 16 + l15) * 128 + kc * 64 + l4 * 16);
        bfr[i][kc] = *(const short8*)(lBb + (wc * 64 + i * 16 + l15) * 128 + kc * 64 + l4 * 16);
      }
    }
#pragma unroll
    for (int i = 0; i < 4; ++i)
#pragma unroll
      for (int j = 0; j < 4; ++j)
#pragma unroll
        for (int kc = 0; kc < 2; ++kc)
          acc[i][j] = mfma16(af[i][kc], bfr[j][kc], acc[i][j]);
    __syncthreads();
  }

#pragma unroll
  for (int i = 0; i < 4; ++i) {
#pragma unroll
    for (int j = 0; j < 4; ++j) {
#pragma unroll
      for (int r = 0; r < 4; ++r) {
        int grow = m0 + wr * 64 + i * 16 + l4 * 4 + r;
        int gcol = n0 + wc * 64 + j * 16 + l15;
        float v = acc[i][j][r];
        if (EPI == 0) {
          int b = grow >> 11, n = grow & (NSEQ - 1);
          int which = gcol >> 10, inner = gcol & 1023;
          int h = inner >> 6, dd = inner & 63;
          size_t off = ((size_t)(b * HEADS + h) * NSEQ + n) * DHEAD + dd;
          if (which == 0)
            q_out[off] = f2bf(v * QSCALE);
          else if (which == 1)
            k_out[off] = f2bf(v);
          else
            v_out[off] = f2bf(v);
        } else {
          outp[(size_t)grow * INNER + gcol] = v + bias[gcol];
        }
      }
    }
  }
}

// ---------------- flash attention: swapped-QK^T, in-register softmax ----------------
// Round-2 structure (measured 78 us) + v_cvt_pk_bf16_f32 packing (only change).
// 1 wave per 32-row Q tile; S^T = mfma32(K, Q): lane owns q-row (lane&31), 16
// key-slots in regs -> row reduce = in-register tree + ONE shfl_xor(32).
// PV as O^T = mfma32(V^T, P^T): O^T col = lane's q-row -> lane-local rescale.
__global__ __launch_bounds__(64) void attn_kernel(
    const ushort* __restrict__ q, const ushort* __restrict__ k,
    const ushort* __restrict__ vt, const int* __restrict__ lens,
    ushort* __restrict__ ctx) {
  const int lane = threadIdx.x;
  const int l31 = lane & 31, hi = lane >> 5;
  const int bid = blockIdx.x;
  const int bh = bid & 31, qt = bid >> 5;        // bh-major in low bits: XCD/L2 clustering
  const int b = bh >> 4, h = bh & 15;
  const int len = lens[b];
  const ushort* qb  = q  + (size_t)bh * NSEQ * DHEAD;
  const ushort* kbp = k  + (size_t)bh * NSEQ * DHEAD;
  const ushort* vtb = vt + (size_t)bh * DHEAD * NSEQ;

  const int qglob = qt * 32 + l31;
  const int qcap  = min(qglob, len - 1);         // valid keys: j <= qcap

  // Q fragments (B-operand of S^T mfma): q-row = l31, d-chunk = dk*16 + hi*8
  short8 qf[4];
#pragma unroll
  for (int dk = 0; dk < 4; ++dk)
    qf[dk] = *(const short8*)&qb[(size_t)(qt * 32 + l31) * DHEAD + dk * 16 + hi * 8];

  f32x16 Ot[2];
#pragma unroll
  for (int d0b = 0; d0b < 2; ++d0b)
#pragma unroll
    for (int r = 0; r < 16; ++r) Ot[d0b][r] = 0.f;
  float mrow = -3.0e38f, lsum = 0.f;

  const int kbend = min(qt, (len - 1) >> 5);

  // prefetch K tile 0 (A-operand: key-row = l31, d-chunk = dk*16 + hi*8)
  short8 kf[4], kn[4];
#pragma unroll
  for (int dk = 0; dk < 4; ++dk)
    kf[dk] = *(const short8*)&kbp[(size_t)l31 * DHEAD + dk * 16 + hi * 8];

  for (int kb = 0; kb <= kbend; ++kb) {
    // ---- S^T = K . Q^T ----
    f32x16 S;
#pragma unroll
    for (int r = 0; r < 16; ++r) S[r] = 0.f;
#pragma unroll
    for (int dk = 0; dk < 4; ++dk) S = mfma32(kf[dk], qf[dk], S);

    // ---- V fragments (A-operand of O^T): d = d0b*32 + l31, n-chunk ks*16+hi*8 ----
    short8 vf[2][2];
#pragma unroll
    for (int d0b = 0; d0b < 2; ++d0b)
#pragma unroll
      for (int ks = 0; ks < 2; ++ks)
        vf[d0b][ks] = *(const short8*)&vtb[(size_t)(d0b * 32 + l31) * NSEQ +
                                           kb * 32 + ks * 16 + hi * 8];

    // ---- prefetch next K tile (latency hidden under softmax) ----
    {
      int kread = min(kb + 1, kbend);
#pragma unroll
      for (int dk = 0; dk < 4; ++dk)
        kn[dk] = *(const short8*)&kbp[(size_t)(kread * 32 + l31) * DHEAD + dk * 16 + hi * 8];
    }

    // ---- mask (wave-uniform fast path skips it) ----
    bool fast = (kb < qt) && (kb * 32 + 31 < len);
    if (!fast) {
      int base = kb * 32 + 4 * hi;
#pragma unroll
      for (int r = 0; r < 16; ++r) {
        int c = (r & 3) + 8 * (r >> 2);
        if (base + c > qcap) S[r] = -3.0e38f;
      }
    }

    // ---- row max: in-register tree + one cross-half shfl ----
    float t0 = fmaxf(S[0], S[1]),  t1 = fmaxf(S[2], S[3]);
    float t2 = fmaxf(S[4], S[5]),  t3 = fmaxf(S[6], S[7]);
    float t4 = fmaxf(S[8], S[9]),  t5 = fmaxf(S[10], S[11]);
    float t6 = fmaxf(S[12], S[13]), t7 = fmaxf(S[14], S[15]);
    t0 = fmaxf(t0, t1); t2 = fmaxf(t2, t3); t4 = fmaxf(t4, t5); t6 = fmaxf(t6, t7);
    float pm = fmaxf(fmaxf(t0, t2), fmaxf(t4, t6));
    pm = fmaxf(pm, __shfl_xor(pm, 32));

    // ---- defer-max (T13, THR=8 in exp2 domain) ----
    if (!__all(pm <= mrow + 8.0f)) {
      float mnew = fmaxf(mrow, pm);
      float scale = exp2f(mrow - mnew);
      lsum *= scale;
#pragma unroll
      for (int d0b = 0; d0b < 2; ++d0b)
#pragma unroll
        for (int r = 0; r < 16; ++r) Ot[d0b][r] *= scale;
      mrow = mnew;
    }

    // ---- p = exp2(S - m); row sum ----
    float p[16];
#pragma unroll
    for (int r = 0; r < 16; ++r) p[r] = exp2f(S[r] - mrow);
    float s0 = (p[0] + p[1]) + (p[2] + p[3]);
    float s1 = (p[4] + p[5]) + (p[6] + p[7]);
    float s2 = (p[8] + p[9]) + (p[10] + p[11]);
    float s3 = (p[12] + p[13]) + (p[14] + p[15]);
    float rs = (s0 + s1) + (s2 + s3);
    rs += __shfl_xor(rs, 32);
    lsum += rs;

    // ---- pack P to bf16 pairs (v_cvt_pk); exchange halves for P^T B-frags ----
    uint Pw[8], Xw[8];
#pragma unroll
    for (int i = 0; i < 8; ++i) Pw[i] = cvtpk(p[2 * i], p[2 * i + 1]);
#pragma unroll
    for (int i = 0; i < 8; ++i) Xw[i] = __shfl_xor(Pw[i], 32);
    uint4v bw0 = { hi ? Xw[2] : Pw[0], hi ? Xw[3] : Pw[1],
                   hi ? Pw[2] : Xw[0], hi ? Pw[3] : Xw[1] };
    uint4v bw1 = { hi ? Xw[6] : Pw[4], hi ? Xw[7] : Pw[5],
                   hi ? Pw[6] : Xw[4], hi ? Pw[7] : Xw[5] };
    short8 pb0 = __builtin_bit_cast(short8, bw0);
    short8 pb1 = __builtin_bit_cast(short8, bw1);

    // ---- O^T += V^T . P^T ----
#pragma unroll
    for (int d0b = 0; d0b < 2; ++d0b) {
      Ot[d0b] = mfma32(vf[d0b][0], pb0, Ot[d0b]);
      Ot[d0b] = mfma32(vf[d0b][1], pb1, Ot[d0b]);
    }

#pragma unroll
    for (int dk = 0; dk < 4; ++dk) kf[dk] = kn[dk];
  }

  // ---- epilogue: O^T col = lane's q-row; rows are d (pairs contiguous) ----
  float inv = 1.0f / lsum;
  size_t rowbase = ((size_t)(b * NSEQ) + qglob) * INNER + h * DHEAD;
#pragma unroll
  for (int d0b = 0; d0b < 2; ++d0b) {
#pragma unroll
    for (int i = 0; i < 8; ++i) {
      int d = 2 * (i & 1) + 8 * (i >> 1) + 4 * hi;   // crow(2i,hi); pair (d, d+1)
      uint w = cvtpk(Ot[d0b][2 * i] * inv, Ot[d0b][2 * i + 1] * inv);
      *(uint*)&ctx[rowbase + d0b * 32 + d] = w;
    }
  }
}

// ---------------- launcher ----------------
extern "C" void kernel_launch(void* const* d_in, const int* in_sizes, int n_in,
                              void* d_out, int out_size, void* d_ws, size_t ws_size,
                              hipStream_t stream) {
  const float* x    = (const float*)d_in[0];
  const int*   mask = (const int*)d_in[1];
  const float* Wqkv = (const float*)d_in[2];
  const float* Wout = (const float*)d_in[3];
  const float* bias = (const float*)d_in[4];
  float* out = (float*)d_out;

  const size_t QKV_ELEMS = (size_t)BATCH * HEADS * NSEQ * DHEAD;

  ushort* ws = (ushort*)d_ws;
  ushort* x_bf  = ws;
  ushort* wq_t  = x_bf  + (size_t)BNROWS * DMODEL;
  ushort* wo_t  = wq_t  + (size_t)NCOL * KDIM;
  ushort* q_bf  = wo_t  + (size_t)INNER * KDIM;
  ushort* k_bf  = q_bf  + QKV_ELEMS;
  ushort* v_bf  = k_bf  + QKV_ELEMS;
  ushort* ctx   = v_bf  + QKV_ELEMS;
  int* lens = (int*)(ctx + (size_t)BNROWS * INNER);
  ushort* vt_bf = x_bf;   // alias: x_bf dead after QKV GEMM

  lens_kernel<<<dim3(BATCH), dim3(256), 0, stream>>>(mask, lens);
  cast_bf16_kernel<<<dim3((BNROWS * DMODEL / 8 + 255) / 256), dim3(256), 0, stream>>>(
      x, x_bf, BNROWS * DMODEL / 8);
  transpose_bf16_kernel<<<dim3(NCOL / 32, KDIM / 32), dim3(32, 8), 0, stream>>>(
      Wqkv, wq_t, KDIM, NCOL);
  transpose_bf16_kernel<<<dim3(INNER / 32, KDIM / 32), dim3(32, 8), 0, stream>>>(
      Wout, wo_t, KDIM, INNER);

  gemm_bt_kernel<0><<<dim3(BNROWS / 128, NCOL / 128), dim3(256), 0, stream>>>(
      x_bf, wq_t, q_bf, k_bf, v_bf, nullptr, nullptr);

  vtrans_kernel<<<dim3(DHEAD / 32, NSEQ / 32, BATCH * HEADS), dim3(32, 8), 0, stream>>>(
      v_bf, vt_bf);

  attn_kernel<<<dim3((NSEQ / 32) * BATCH * HEADS), dim3(64), 0, stream>>>(
      q_bf, k_bf, vt_bf, lens, ctx);

  gemm_bt_kernel<1><<<dim3(BNROWS / 128, INNER / 128), dim3(256), 0, stream>>>(
      ctx, wo_t, nullptr, nullptr, nullptr, bias, out);
}

// Round 11
// 237.427 us; speedup vs baseline: 1.0155x; 1.0004x over previous
//
#include <hip/hip_runtime.h>

// ---------------- constants ----------------
#define BATCH   2
#define NSEQ    2048
#define DMODEL  1024
#define HEADS   16
#define DHEAD   64
#define INNER   1024      // HEADS*DHEAD
#define NCOL    3072      // 3*INNER
#define BNROWS  4096      // BATCH*NSEQ
#define KDIM    1024      // contraction dim for both GEMMs

typedef unsigned short ushort;
typedef unsigned int   uint;
typedef __attribute__((ext_vector_type(8)))  short  short8;
typedef __attribute__((ext_vector_type(4)))  float  f32x4;
typedef __attribute__((ext_vector_type(16))) float  f32x16;
typedef __attribute__((ext_vector_type(8)))  ushort ushort8;
typedef __attribute__((ext_vector_type(4)))  float  f4v;
typedef __attribute__((ext_vector_type(4)))  uint   uint4v;

// SCALE * log2(e) so softmax can use exp2 directly
#define QSCALE 0.1803368801111204f   // 64^-0.5 * 1.4426950408889634

__device__ __forceinline__ ushort f2bf(float f) {
  uint u = __builtin_bit_cast(uint, f);
  u += 0x7fffu + ((u >> 16) & 1u);   // RNE
  return (ushort)(u >> 16);
}
// single-op packed f32->bf16 (T12; no builtin on gfx950, RNE)
__device__ __forceinline__ uint cvtpk(float a, float b) {
  uint r;
  asm("v_cvt_pk_bf16_f32 %0, %1, %2" : "=v"(r) : "v"(a), "v"(b));
  return r;
}

__device__ __forceinline__ f32x4 mfma16(short8 a, short8 b, f32x4 c) {
  return __builtin_amdgcn_mfma_f32_16x16x32_bf16(a, b, c, 0, 0, 0);
}
__device__ __forceinline__ f32x16 mfma32(short8 a, short8 b, f32x16 c) {
  return __builtin_amdgcn_mfma_f32_32x32x16_bf16(a, b, c, 0, 0, 0);
}

#define GLDS(gp, lp) __builtin_amdgcn_global_load_lds( \
    (const __attribute__((address_space(1))) void*)(gp), \
    (__attribute__((address_space(3))) void*)(lp), 16, 0, 0)

// ---------------- lengths from mask (int32 0/1) ----------------
__global__ __launch_bounds__(256) void lens_kernel(const int* __restrict__ mask,
                                                   int* __restrict__ lens) {
  __shared__ int sm[256];
  int b = blockIdx.x, t = threadIdx.x;
  int s = 0;
  for (int i = t; i < NSEQ; i += 256) s += (mask[b * NSEQ + i] != 0);
  sm[t] = s;
  __syncthreads();
  for (int off = 128; off > 0; off >>= 1) {
    if (t < off) sm[t] += sm[t + off];
    __syncthreads();
  }
  if (t == 0) lens[b] = sm[0];
}

// ---------------- fp32 -> bf16 cast (vectorized) ----------------
__global__ __launch_bounds__(256) void cast_bf16_kernel(const float* __restrict__ x,
                                                        ushort* __restrict__ y, int n8) {
  int i = blockIdx.x * 256 + threadIdx.x;
  if (i >= n8) return;
  const f4v* xv = (const f4v*)x;
  f4v a = xv[(size_t)i * 2], b = xv[(size_t)i * 2 + 1];
  ushort8 o;
  o[0] = f2bf(a[0]); o[1] = f2bf(a[1]); o[2] = f2bf(a[2]); o[3] = f2bf(a[3]);
  o[4] = f2bf(b[0]); o[5] = f2bf(b[1]); o[6] = f2bf(b[2]); o[7] = f2bf(b[3]);
  ((ushort8*)y)[i] = o;
}

// ---------------- fp32 (K,C) -> bf16 transposed (C,K) ----------------
__global__ __launch_bounds__(256) void transpose_bf16_kernel(const float* __restrict__ W,
                                                             ushort* __restrict__ Wt,
                                                             int K, int C) {
  __shared__ float tile[32][33];
  int c0 = blockIdx.x * 32, k0 = blockIdx.y * 32;
  int tx = threadIdx.x, ty = threadIdx.y;   // (32,8)
#pragma unroll
  for (int i = 0; i < 4; ++i)
    tile[ty + i * 8][tx] = W[(size_t)(k0 + ty + i * 8) * C + c0 + tx];
  __syncthreads();
#pragma unroll
  for (int i = 0; i < 4; ++i)
    Wt[(size_t)(c0 + ty + i * 8) * K + k0 + tx] = f2bf(tile[tx][ty + i * 8]);
}

// ---------------- bf16 (bh, n, d) -> (bh, d, n) transpose for V ----------------
__global__ __launch_bounds__(256) void vtrans_kernel(const ushort* __restrict__ v,
                                                     ushort* __restrict__ vt) {
  __shared__ ushort t[32][34];
  int d0 = blockIdx.x * 32, n0 = blockIdx.y * 32, bh = blockIdx.z;
  const ushort* vb  = v  + (size_t)bh * NSEQ * DHEAD;
  ushort*       vtb = vt + (size_t)bh * NSEQ * DHEAD;
  int tx = threadIdx.x, ty = threadIdx.y;   // (32,8)
#pragma unroll
  for (int i = 0; i < 4; ++i)
    t[ty + i * 8][tx] = vb[(size_t)(n0 + ty + i * 8) * DHEAD + d0 + tx];
  __syncthreads();
#pragma unroll
  for (int i = 0; i < 4; ++i)
    vtb[(size_t)(d0 + ty + i * 8) * NSEQ + n0 + tx] = t[tx][ty + i * 8];
}

// ---------------- m97-style bf16 GEMM, C = A(M,K) @ Bt(N,K)^T ----------------
template <int EPI>
__global__ __launch_bounds__(256) void gemm_bt_kernel(
    const ushort* __restrict__ A, const ushort* __restrict__ Bt,
    ushort* __restrict__ q_out, ushort* __restrict__ k_out, ushort* __restrict__ v_out,
    const float* __restrict__ bias, float* __restrict__ outp) {
  __shared__ __align__(16) ushort lA[128 * 64];
  __shared__ __align__(16) ushort lB[128 * 64];
  const int tid = threadIdx.x;
  const int wv = tid >> 6, lane = tid & 63;
  const int wr = wv >> 1, wc = wv & 1;
  const int m0 = blockIdx.x * 128, n0 = blockIdx.y * 128;
  const int l15 = lane & 15, l4 = lane >> 4;

  f32x4 zero = {0.f, 0.f, 0.f, 0.f};
  f32x4 acc[4][4];
#pragma unroll
  for (int i = 0; i < 4; ++i)
#pragma unroll
    for (int j = 0; j < 4; ++j) acc[i][j] = zero;

  const char* Ab  = (const char*)A;
  const char* Bb  = (const char*)Bt;
  char* lAb = (char*)lA;
  char* lBb = (char*)lB;

  for (int kt = 0; kt < KDIM; kt += 64) {
#pragma unroll
    for (int t = 0; t < 4; ++t) {
      int o = wv * 4096 + t * 1024 + lane * 16;
      int row = o >> 7, cb = o & 127;
      GLDS(Ab + ((size_t)(m0 + row) * KDIM + kt) * 2 + cb, lAb + o);
      GLDS(Bb + ((size_t)(n0 + row) * KDIM + kt) * 2 + cb, lBb + o);
    }
    __syncthreads();

    short8 af[4][2], bfr[4][2];
#pragma unroll
    for (int i = 0; i < 4; ++i) {
#pragma unroll
      for (int kc = 0; kc < 2; ++kc) {
        af[i][kc]  = *(const short8*)(lAb + (wr * 64 + i * 16 + l15) * 128 + kc * 64 + l4 * 16);
        bfr[i][kc] = *(const short8*)(lBb + (wc * 64 + i * 16 + l15) * 128 + kc * 64 + l4 * 16);
      }
    }
#pragma unroll
    for (int i = 0; i < 4; ++i)
#pragma unroll
      for (int j = 0; j < 4; ++j)
#pragma unroll
        for (int kc = 0; kc < 2; ++kc)
          acc[i][j] = mfma16(af[i][kc], bfr[j][kc], acc[i][j]);
    __syncthreads();
  }

#pragma unroll
  for (int i = 0; i < 4; ++i) {
#pragma unroll
    for (int j = 0; j < 4; ++j) {
#pragma unroll
      for (int r = 0; r < 4; ++r) {
        int grow = m0 + wr * 64 + i * 16 + l4 * 4 + r;
        int gcol = n0 + wc * 64 + j * 16 + l15;
        float v = acc[i][j][r];
        if (EPI == 0) {
          int b = grow >> 11, n = grow & (NSEQ - 1);
          int which = gcol >> 10, inner = gcol & 1023;
          int h = inner >> 6, dd = inner & 63;
          size_t off = ((size_t)(b * HEADS + h) * NSEQ + n) * DHEAD + dd;
          if (which == 0)
            q_out[off] = f2bf(v * QSCALE);
          else if (which == 1)
            k_out[off] = f2bf(v);
          else
            v_out[off] = f2bf(v);
        } else {
          outp[(size_t)grow * INNER + gcol] = v + bias[gcol];
        }
      }
    }
  }
}

// ---------------- flash attention: swapped-QK^T, split-K across 2 waves ----------------
// 1 block (2 waves, 128 thr) per 32-row Q tile. Wave w handles key-tiles
// kb ≡ w (mod 2) with the round-9-verified inner loop; partials merged via LDS
// (flash combine) at the end. Doubles resident waves (16/CU) to hide K/V + exp2
// latency; halves per-wave work (halves the causal drain tail).
__global__ __launch_bounds__(128, 4) void attn_kernel(
    const ushort* __restrict__ q, const ushort* __restrict__ k,
    const ushort* __restrict__ vt, const int* __restrict__ lens,
    ushort* __restrict__ ctx) {
  __shared__ float lred[64 * 33 + 64];          // wave1 O (padded) + m + l
  const int tid  = threadIdx.x;
  const int wave = tid >> 6, lane = tid & 63;
  const int l31 = lane & 31, hi = lane >> 5;
  const int bid = blockIdx.x;
  const int bh = bid & 31, qt = bid >> 5;        // bh-major: XCD/L2 clustering
  const int b = bh >> 4, h = bh & 15;
  const int len = lens[b];
  const ushort* qb  = q  + (size_t)bh * NSEQ * DHEAD;
  const ushort* kbp = k  + (size_t)bh * NSEQ * DHEAD;
  const ushort* vtb = vt + (size_t)bh * DHEAD * NSEQ;

  const int qglob = qt * 32 + l31;
  const int qcap  = min(qglob, len - 1);         // valid keys: j <= qcap

  // Q fragments (B-operand of S^T mfma): q-row = l31, d-chunk = dk*16 + hi*8
  short8 qf[4];
#pragma unroll
  for (int dk = 0; dk < 4; ++dk)
    qf[dk] = *(const short8*)&qb[(size_t)(qt * 32 + l31) * DHEAD + dk * 16 + hi * 8];

  f32x16 Ot[2];
#pragma unroll
  for (int d0b = 0; d0b < 2; ++d0b)
#pragma unroll
    for (int r = 0; r < 16; ++r) Ot[d0b][r] = 0.f;
  float mrow = -3.0e38f, lsum = 0.f;

  const int kbend = min(qt, (len - 1) >> 5);

  // prefetch this wave's first K tile (clamped; unused if wave has no tiles)
  short8 kf[4], kn[4];
  {
    int k0t = min(wave, kbend);
#pragma unroll
    for (int dk = 0; dk < 4; ++dk)
      kf[dk] = *(const short8*)&kbp[(size_t)(k0t * 32 + l31) * DHEAD + dk * 16 + hi * 8];
  }

  for (int kb = wave; kb <= kbend; kb += 2) {
    // ---- S^T = K . Q^T ----
    f32x16 S;
#pragma unroll
    for (int r = 0; r < 16; ++r) S[r] = 0.f;
#pragma unroll
    for (int dk = 0; dk < 4; ++dk) S = mfma32(kf[dk], qf[dk], S);

    // ---- V fragments (A-operand of O^T): d = d0b*32 + l31, n-chunk ks*16+hi*8 ----
    short8 vf[2][2];
#pragma unroll
    for (int d0b = 0; d0b < 2; ++d0b)
#pragma unroll
      for (int ks = 0; ks < 2; ++ks)
        vf[d0b][ks] = *(const short8*)&vtb[(size_t)(d0b * 32 + l31) * NSEQ +
                                           kb * 32 + ks * 16 + hi * 8];

    // ---- prefetch next K tile of this wave (hidden under softmax) ----
    {
      int kread = min(kb + 2, kbend);
#pragma unroll
      for (int dk = 0; dk < 4; ++dk)
        kn[dk] = *(const short8*)&kbp[(size_t)(kread * 32 + l31) * DHEAD + dk * 16 + hi * 8];
    }

    // ---- mask (wave-uniform fast path skips it) ----
    bool fast = (kb < qt) && (kb * 32 + 31 < len);
    if (!fast) {
      int base = kb * 32 + 4 * hi;
#pragma unroll
      for (int r = 0; r < 16; ++r) {
        int c = (r & 3) + 8 * (r >> 2);
        if (base + c > qcap) S[r] = -3.0e38f;
      }
    }

    // ---- row max: in-register tree + one cross-half shfl ----
    float t0 = fmaxf(S[0], S[1]),  t1 = fmaxf(S[2], S[3]);
    float t2 = fmaxf(S[4], S[5]),  t3 = fmaxf(S[6], S[7]);
    float t4 = fmaxf(S[8], S[9]),  t5 = fmaxf(S[10], S[11]);
    float t6 = fmaxf(S[12], S[13]), t7 = fmaxf(S[14], S[15]);
    t0 = fmaxf(t0, t1); t2 = fmaxf(t2, t3); t4 = fmaxf(t4, t5); t6 = fmaxf(t6, t7);
    float pm = fmaxf(fmaxf(t0, t2), fmaxf(t4, t6));
    pm = fmaxf(pm, __shfl_xor(pm, 32));

    // ---- defer-max (T13, THR=8 in exp2 domain) ----
    if (!__all(pm <= mrow + 8.0f)) {
      float mnew = fmaxf(mrow, pm);
      float scale = exp2f(mrow - mnew);
      lsum *= scale;
#pragma unroll
      for (int d0b = 0; d0b < 2; ++d0b)
#pragma unroll
        for (int r = 0; r < 16; ++r) Ot[d0b][r] *= scale;
      mrow = mnew;
    }

    // ---- p = exp2(S - m); row sum ----
    float p[16];
#pragma unroll
    for (int r = 0; r < 16; ++r) p[r] = exp2f(S[r] - mrow);
    float s0 = (p[0] + p[1]) + (p[2] + p[3]);
    float s1 = (p[4] + p[5]) + (p[6] + p[7]);
    float s2 = (p[8] + p[9]) + (p[10] + p[11]);
    float s3 = (p[12] + p[13]) + (p[14] + p[15]);
    float rs = (s0 + s1) + (s2 + s3);
    rs += __shfl_xor(rs, 32);
    lsum += rs;

    // ---- pack P to bf16 pairs (v_cvt_pk); exchange halves for P^T B-frags ----
    uint Pw[8], Xw[8];
#pragma unroll
    for (int i = 0; i < 8; ++i) Pw[i] = cvtpk(p[2 * i], p[2 * i + 1]);
#pragma unroll
    for (int i = 0; i < 8; ++i) Xw[i] = __shfl_xor(Pw[i], 32);
    uint4v bw0 = { hi ? Xw[2] : Pw[0], hi ? Xw[3] : Pw[1],
                   hi ? Pw[2] : Xw[0], hi ? Pw[3] : Xw[1] };
    uint4v bw1 = { hi ? Xw[6] : Pw[4], hi ? Xw[7] : Pw[5],
                   hi ? Pw[6] : Xw[4], hi ? Pw[7] : Xw[5] };
    short8 pb0 = __builtin_bit_cast(short8, bw0);
    short8 pb1 = __builtin_bit_cast(short8, bw1);

    // ---- O^T += V^T . P^T ----
#pragma unroll
    for (int d0b = 0; d0b < 2; ++d0b) {
      Ot[d0b] = mfma32(vf[d0b][0], pb0, Ot[d0b]);
      Ot[d0b] = mfma32(vf[d0b][1], pb1, Ot[d0b]);
    }

#pragma unroll
    for (int dk = 0; dk < 4; ++dk) kf[dk] = kn[dk];
  }

  // ---- merge wave1 partials into wave0 (flash combine), then store ----
  if (wave == 1) {
#pragma unroll
    for (int d0b = 0; d0b < 2; ++d0b)
#pragma unroll
      for (int r = 0; r < 16; ++r) lred[lane * 33 + d0b * 16 + r] = Ot[d0b][r];
    if (hi == 0) {
      lred[64 * 33 + l31]      = mrow;
      lred[64 * 33 + 32 + l31] = lsum;
    }
  }
  __syncthreads();
  if (wave == 0) {
    float m1 = lred[64 * 33 + l31];
    float l1 = lred[64 * 33 + 32 + l31];
    float ms = fmaxf(mrow, m1);
    float al = exp2f(mrow - ms);
    float be = exp2f(m1 - ms);
    float lt = lsum * al + l1 * be;
    float inv = 1.0f / lt;
    size_t rowbase = ((size_t)(b * NSEQ) + qglob) * INNER + h * DHEAD;
#pragma unroll
    for (int d0b = 0; d0b < 2; ++d0b) {
#pragma unroll
      for (int i = 0; i < 8; ++i) {
        float oa = (Ot[d0b][2 * i]     * al + lred[lane * 33 + d0b * 16 + 2 * i]     * be) * inv;
        float ob = (Ot[d0b][2 * i + 1] * al + lred[lane * 33 + d0b * 16 + 2 * i + 1] * be) * inv;
        int d = 2 * (i & 1) + 8 * (i >> 1) + 4 * hi;   // crow(2i,hi); pair (d, d+1)
        *(uint*)&ctx[rowbase + d0b * 32 + d] = cvtpk(oa, ob);
      }
    }
  }
}

// ---------------- launcher ----------------
extern "C" void kernel_launch(void* const* d_in, const int* in_sizes, int n_in,
                              void* d_out, int out_size, void* d_ws, size_t ws_size,
                              hipStream_t stream) {
  const float* x    = (const float*)d_in[0];
  const int*   mask = (const int*)d_in[1];
  const float* Wqkv = (const float*)d_in[2];
  const float* Wout = (const float*)d_in[3];
  const float* bias = (const float*)d_in[4];
  float* out = (float*)d_out;

  const size_t QKV_ELEMS = (size_t)BATCH * HEADS * NSEQ * DHEAD;

  ushort* ws = (ushort*)d_ws;
  ushort* x_bf  = ws;
  ushort* wq_t  = x_bf  + (size_t)BNROWS * DMODEL;
  ushort* wo_t  = wq_t  + (size_t)NCOL * KDIM;
  ushort* q_bf  = wo_t  + (size_t)INNER * KDIM;
  ushort* k_bf  = q_bf  + QKV_ELEMS;
  ushort* v_bf  = k_bf  + QKV_ELEMS;
  ushort* ctx   = v_bf  + QKV_ELEMS;
  int* lens = (int*)(ctx + (size_t)BNROWS * INNER);
  ushort* vt_bf = x_bf;   // alias: x_bf dead after QKV GEMM

  lens_kernel<<<dim3(BATCH), dim3(256), 0, stream>>>(mask, lens);
  cast_bf16_kernel<<<dim3((BNROWS * DMODEL / 8 + 255) / 256), dim3(256), 0, stream>>>(
      x, x_bf, BNROWS * DMODEL / 8);
  transpose_bf16_kernel<<<dim3(NCOL / 32, KDIM / 32), dim3(32, 8), 0, stream>>>(
      Wqkv, wq_t, KDIM, NCOL);
  transpose_bf16_kernel<<<dim3(INNER / 32, KDIM / 32), dim3(32, 8), 0, stream>>>(
      Wout, wo_t, KDIM, INNER);

  gemm_bt_kernel<0><<<dim3(BNROWS / 128, NCOL / 128), dim3(256), 0, stream>>>(
      x_bf, wq_t, q_bf, k_bf, v_bf, nullptr, nullptr);

  vtrans_kernel<<<dim3(DHEAD / 32, NSEQ / 32, BATCH * HEADS), dim3(32, 8), 0, stream>>>(
      v_bf, vt_bf);

  attn_kernel<<<dim3((NSEQ / 32) * BATCH * HEADS), dim3(128), 0, stream>>>(
      q_bf, k_bf, vt_bf, lens, ctx);

  gemm_bt_kernel<1><<<dim3(BNROWS / 128, INNER / 128), dim3(256), 0, stream>>>(
      ctx, wo_t, nullptr, nullptr, nullptr, bias, out);
}